// Round 10
// baseline (158.382 us; speedup 1.0000x reference)
//
#include <hip/hip_runtime.h>

typedef __attribute__((ext_vector_type(8))) short short8;
typedef __attribute__((ext_vector_type(4))) short short4v;
typedef __attribute__((ext_vector_type(4))) float f32x4;

__device__ __forceinline__ short f2bf(float f) {
  unsigned u = __builtin_bit_cast(unsigned, f);
  u = u + 0x7fffu + ((u >> 16) & 1u);
  return (short)(u >> 16);
}

// ---------------- fused: gn_stats + weight cast (wq,wk) + lsum zero
// blk 0..1023: GN partials; 1024..2047: wcast (full 262144 coverage);
// 2048..2051: zero lsum (16K f32).
__global__ __launch_bounds__(256) void pre_kernel(
    const float* __restrict__ x, float2* __restrict__ part,
    const float* __restrict__ wq, const float* __restrict__ wk,
    short* __restrict__ wout, float* __restrict__ lz) {
  const int blk = blockIdx.x, t = threadIdx.x;
  if (blk < 1024) {
    const float* base = x + (long)blk * 8192;
    float s = 0.f, ss = 0.f;
#pragma unroll
    for (int j = 0; j < 8; ++j) {
      float4 v = ((const float4*)base)[t + j * 256];
      s  += v.x + v.y + v.z + v.w;
      ss += v.x * v.x + v.y * v.y + v.z * v.z + v.w * v.w;
    }
    for (int o = 32; o > 0; o >>= 1) { s += __shfl_xor(s, o, 64); ss += __shfl_xor(ss, o, 64); }
    __shared__ float rs[4], rss[4];
    if ((t & 63) == 0) { rs[t >> 6] = s; rss[t >> 6] = ss; }
    __syncthreads();
    if (t == 0) {
      part[blk] = make_float2(rs[0] + rs[1] + rs[2] + rs[3],
                              rss[0] + rss[1] + rss[2] + rss[3]);
    }
  } else if (blk < 2048) {
    int i = (blk - 1024) * 256 + t;  // 0..262143
    wout[i]          = f2bf(wq[i]);
    wout[262144 + i] = f2bf(wk[i]);
  } else {
    float4* p = (float4*)lz;
    const int base = (blk - 2048) * 1024 + t * 4;
#pragma unroll
    for (int k = 0; k < 4; ++k) p[base + k] = make_float4(0.f, 0.f, 0.f, 0.f);
  }
}

// ---------------- W' = wp . wv  (bf16, [512][512]) + bias2 = bp + wp.bv
// Tiny one-off GEMM: 16 blocks, reads f32 weights directly, LDS-staged.
__global__ __launch_bounds__(256) void wprime_kernel(
    const float* __restrict__ wv, const float* __restrict__ wp,
    const float* __restrict__ bv, const float* __restrict__ bp,
    short* __restrict__ Wp, float* __restrict__ bias2) {
  __shared__ short Ab[128][72];
  __shared__ short Bb[128][72];
  const int m0 = blockIdx.y * 128, n0 = blockIdx.x * 128;
  const int tid = threadIdx.x, lane = tid & 63, w = tid >> 6;
  const int wm = (w >> 1) * 64, wn = (w & 1) * 64;
  const int g = lane >> 4, ar = lane & 15;
  f32x4 acc[4][4] = {};
  for (int c0 = 0; c0 < 512; c0 += 64) {
    __syncthreads();
    {
      // A tile: wp[m0+row][c0 + half*32 .. +32)
      const int row = tid >> 1, half = tid & 1;
      const float* src = wp + (long)(m0 + row) * 512 + c0 + half * 32;
      short tmp[32];
#pragma unroll
      for (int q = 0; q < 8; ++q) {
        float4 v = ((const float4*)src)[q];
        tmp[q * 4 + 0] = f2bf(v.x); tmp[q * 4 + 1] = f2bf(v.y);
        tmp[q * 4 + 2] = f2bf(v.z); tmp[q * 4 + 3] = f2bf(v.w);
      }
#pragma unroll
      for (int q = 0; q < 4; ++q)
        *(short8*)&Ab[row][half * 32 + q * 8] = *(short8*)&tmp[q * 8];
      // B tile (transposed): Bb[e][c] = wv[c0+cc][n0+e]
      const int cc = tid >> 2, e0 = (tid & 3) * 32;
      const float* srcb = wv + (long)(c0 + cc) * 512 + n0 + e0;
#pragma unroll
      for (int q = 0; q < 8; ++q) {
        float4 v = ((const float4*)srcb)[q];
        Bb[e0 + q * 4 + 0][cc] = f2bf(v.x);
        Bb[e0 + q * 4 + 1][cc] = f2bf(v.y);
        Bb[e0 + q * 4 + 2][cc] = f2bf(v.z);
        Bb[e0 + q * 4 + 3][cc] = f2bf(v.w);
      }
    }
    __syncthreads();
#pragma unroll
    for (int kk = 0; kk < 2; ++kk) {
      const int kf = kk * 32 + g * 8;
      short8 af[4], bf[4];
#pragma unroll
      for (int i = 0; i < 4; ++i) {
        af[i] = *(const short8*)&Ab[wm + i * 16 + ar][kf];
        bf[i] = *(const short8*)&Bb[wn + i * 16 + ar][kf];
      }
#pragma unroll
      for (int i = 0; i < 4; ++i)
#pragma unroll
        for (int j = 0; j < 4; ++j)
          acc[i][j] = __builtin_amdgcn_mfma_f32_16x16x32_bf16(af[i], bf[j], acc[i][j], 0, 0, 0);
    }
  }
  const int mb = m0 + wm + (lane >> 4) * 4;
  const int nb = n0 + wn + ar;
#pragma unroll
  for (int i = 0; i < 4; ++i)
#pragma unroll
    for (int r = 0; r < 4; ++r) {
      int m = mb + i * 16 + r;
#pragma unroll
      for (int j = 0; j < 4; ++j)
        Wp[(long)m * 512 + nb + j * 16] = f2bf(acc[i][j][r]);
    }
  if (n0 == 0 && tid < 128) {
    int m = m0 + tid;
    float s = bp[m];
    const float* wr = wp + (long)m * 512;
    for (int c = 0; c < 512; ++c) s += wr[c] * bv[c];
    bias2[m] = s;
  }
}

// ---------------- GN pass 2: normalize + transpose to xnt[B,N,C]
#define TP 133
__global__ __launch_bounds__(256) void gn_norm_t(
    const float* __restrict__ x, const float2* __restrict__ part,
    const float* __restrict__ gamma, const float* __restrict__ beta,
    short* __restrict__ xnt) {
  const int blk = blockIdx.x;
  const int nc = blk & 7, g = (blk >> 3) & 7, b = blk >> 6;
  const int t = threadIdx.x;
  float s = 0.f, ss = 0.f;
#pragma unroll
  for (int j = 0; j < 8; ++j) {
    float2 p = part[(b * 8 + g) * 8 + j];
    s += p.x; ss += p.y;
  }
  const float mean = s * (1.f / 65536.f);
  const float var  = ss * (1.f / 65536.f) - mean * mean;
  const float rstd = rsqrtf(var + 1e-5f);

  const float* base = x + (long)(b * 512 + g * 64) * 1024 + nc * 128;
  __shared__ float tile[64][TP];
  const int row = t >> 2, c4 = t & 3;
#pragma unroll
  for (int j = 0; j < 8; ++j) {
    float4 v = *(const float4*)(base + (long)row * 1024 + (c4 + j * 4) * 4);
    *(float4*)&tile[row][(c4 + j * 4) * 4] = v;
  }
  const int cl4 = (t & 15) * 4;
  float ga[4], be[4];
#pragma unroll
  for (int j = 0; j < 4; ++j) {
    float gm = gamma[g * 64 + cl4 + j];
    ga[j] = gm * rstd;
    be[j] = beta[g * 64 + cl4 + j] - mean * ga[j];
  }
  __syncthreads();
  short* outb = xnt + (long)b * 524288 + (long)(nc * 128) * 512 + g * 64 + cl4;
#pragma unroll
  for (int it = 0; it < 8; ++it) {
    const int tok = (t >> 4) + it * 16;
    short4v o;
    o.x = f2bf(tile[cl4 + 0][tok] * ga[0] + be[0]);
    o.y = f2bf(tile[cl4 + 1][tok] * ga[1] + be[1]);
    o.z = f2bf(tile[cl4 + 2][tok] * ga[2] + be[2]);
    o.w = f2bf(tile[cl4 + 3][tok] * ga[3] + be[3]);
    *(short4v*)(outb + (long)tok * 512) = o;
  }
}

// ---------------- GEMM core (round-3/6 proven: single-buffer, 2-barrier)
// C[M,N] = A[M,K] * Bt[N,K]^T, bf16 row-major, 128x128 tile, BK=64, 4 waves.
#define BM 128
#define BK 64
enum { EPI_EXP_T = 3, EPI_OUT = 5 };

__device__ __forceinline__ int swz_idx(int row, int k) {
  return row * 64 + ((((k >> 3) ^ row) & 7) << 3) + (k & 7);
}

__device__ __forceinline__ void gemm_core(
    const short* __restrict__ Ab, const short* __restrict__ Bb,
    short* lds, f32x4 (&acc)[4][4], int m0, int n0, int K, int tid) {
  const int lane = tid & 63, w = tid >> 6;
  const int wm = (w >> 1) * 64, wn = (w & 1) * 64;
  const int rowst = w * 32 + (lane >> 3);
  for (int k0 = 0; k0 < K; k0 += BK) {
    __syncthreads();
#pragma unroll
    for (int it = 0; it < 4; ++it) {
      int ci = w * 4 + it;
      int row = rowst + it * 8;
      int slot = (lane & 7) ^ (row & 7);
      const short* ga = Ab + (long)(m0 + row) * K + k0 + slot * 8;
      __builtin_amdgcn_global_load_lds(
          (const __attribute__((address_space(1))) void*)ga,
          (__attribute__((address_space(3))) void*)(lds + ci * 512), 16, 0, 0);
      const short* gb = Bb + (long)(n0 + row) * K + k0 + slot * 8;
      __builtin_amdgcn_global_load_lds(
          (const __attribute__((address_space(1))) void*)gb,
          (__attribute__((address_space(3))) void*)(lds + 8192 + ci * 512), 16, 0, 0);
    }
    __syncthreads();
#pragma unroll
    for (int kk = 0; kk < 2; ++kk) {
      short8 af[4], bf[4];
      const int kf = kk * 32 + (lane >> 4) * 8;
#pragma unroll
      for (int i = 0; i < 4; ++i) {
        af[i] = *(const short8*)(lds + swz_idx(wm + i * 16 + (lane & 15), kf));
        bf[i] = *(const short8*)(lds + 8192 + swz_idx(wn + i * 16 + (lane & 15), kf));
      }
#pragma unroll
      for (int i = 0; i < 4; ++i)
#pragma unroll
        for (int j = 0; j < 4; ++j)
          acc[i][j] = __builtin_amdgcn_mfma_f32_16x16x32_bf16(af[i], bf[j], acc[i][j], 0, 0, 0);
    }
  }
}

// ---------------- fused Q/K/U projection GEMM
// A = stacked [wq; wk; W'] = [1536,512] bf16. grid (8, 12, 16).
// y 0..3 -> q_t (trans packed), 4..7 -> k_t (trans packed),
// 8..11 -> u[o][tok] ([512,1024] bf16, no bias).
__global__ __launch_bounds__(256, 3) void qku_gemm(
    const short* __restrict__ W, const short* __restrict__ xnt,
    short* __restrict__ q_t, short* __restrict__ k_t, short* __restrict__ u,
    const float* __restrict__ bq, const float* __restrict__ bk) {
  __shared__ short lds[2 * BM * BK];
  const int b = blockIdx.z, y = blockIdx.y;
  const int which = y >> 2;
  const int m0 = y * BM;
  const int mloc0 = m0 - which * 512;
  const int n0 = blockIdx.x * BM;
  const short* Bb = xnt + (long)b * 524288;
  const int tid = threadIdx.x, lane = tid & 63, w = tid >> 6;
  f32x4 acc[4][4] = {};
  gemm_core(W, Bb, lds, acc, m0, n0, 512, tid);

  const int wm = (w >> 1) * 64, wn = (w & 1) * 64;
  const int mb = mloc0 + wm + (lane >> 4) * 4;
  const int nb = n0 + wn + (lane & 15);
  if (which < 2) {
    short* C = (which ? k_t : q_t) + (long)b * 524288;
    const float* bias = which ? bk : bq;
#pragma unroll
    for (int i = 0; i < 4; ++i) {
      int m = mb + i * 16;
      float b0 = bias[m], b1 = bias[m + 1], b2 = bias[m + 2], b3 = bias[m + 3];
#pragma unroll
      for (int j = 0; j < 4; ++j) {
        int n = nb + j * 16;
        short4v o;
        o.x = f2bf(acc[i][j][0] + b0);
        o.y = f2bf(acc[i][j][1] + b1);
        o.z = f2bf(acc[i][j][2] + b2);
        o.w = f2bf(acc[i][j][3] + b3);
        *(short4v*)(C + (long)n * 512 + m) = o;  // [tok][ch]
      }
    }
  } else {
    short* C = u + (long)b * 524288;  // [o][tok], stride 1024
#pragma unroll
    for (int i = 0; i < 4; ++i) {
#pragma unroll
      for (int r = 0; r < 4; ++r) {
        int m = mb + i * 16 + r;
#pragma unroll
        for (int j = 0; j < 4; ++j) {
          int n = nb + j * 16;
          C[(long)m * 1024 + n] = f2bf(acc[i][j][r]);
        }
      }
    }
  }
}

// ---------------- generic GEMM (S-exp / final out)
template <int EPI>
__global__ __launch_bounds__(256, 3) void gemm_bt(
    const short* __restrict__ A, const short* __restrict__ Bt,
    void* __restrict__ Cv, const float* __restrict__ bias,
    const float* __restrict__ resid, float scale,
    int M, int N, int K, long aStr, long bStr, long cStr, long rStr,
    float* __restrict__ lsum) {
  __shared__ short lds[2 * BM * BK];
  const int b = blockIdx.z;
  const short* Ab = A + (long)b * aStr;
  const short* Bb = Bt + (long)b * bStr;
  const int m0 = blockIdx.y * BM, n0 = blockIdx.x * BM;
  const int tid = threadIdx.x, lane = tid & 63, w = tid >> 6;
  f32x4 acc[4][4] = {};
  gemm_core(Ab, Bb, lds, acc, m0, n0, K, tid);

  const int wm = (w >> 1) * 64, wn = (w & 1) * 64;
  const int mb = m0 + wm + (lane >> 4) * 4;
  const int nb = n0 + wn + (lane & 15);
  if constexpr (EPI == EPI_EXP_T) {
    // A=keys, Bt=queries. Write P' = exp(S*scale) transposed: C[q*M + key],
    // packed 8B along keys; accumulate per-query row sums into lsum[b][q].
    short* C = (short*)Cv + (long)b * cStr;
    float rowsum[4] = {0.f, 0.f, 0.f, 0.f};
#pragma unroll
    for (int j = 0; j < 4; ++j) {
      int n = nb + j * 16;  // query
#pragma unroll
      for (int i = 0; i < 4; ++i) {
        int m = mb + i * 16;  // key
        float e0 = __expf(acc[i][j][0] * scale);
        float e1 = __expf(acc[i][j][1] * scale);
        float e2 = __expf(acc[i][j][2] * scale);
        float e3 = __expf(acc[i][j][3] * scale);
        rowsum[j] += (e0 + e1) + (e2 + e3);
        short4v o;
        o.x = f2bf(e0); o.y = f2bf(e1); o.z = f2bf(e2); o.w = f2bf(e3);
        *(short4v*)(C + (long)n * M + m) = o;
      }
    }
#pragma unroll
    for (int j = 0; j < 4; ++j) {
      rowsum[j] += __shfl_xor(rowsum[j], 16, 64);
      rowsum[j] += __shfl_xor(rowsum[j], 32, 64);
    }
    if (lane < 16) {
#pragma unroll
      for (int j = 0; j < 4; ++j)
        atomicAdd(&lsum[b * 1024 + nb + j * 16], rowsum[j]);
    }
  } else {  // EPI_OUT: A=u[o][j], Bt=P'[i][j]. out = acc/lsum[i] + bias2[o] + x
    float* C = (float*)Cv + (long)b * cStr;
    const float* R = resid + (long)b * rStr;
#pragma unroll
    for (int j = 0; j < 4; ++j) {
      int n = nb + j * 16;  // query i
      float rl = 1.0f / lsum[b * 1024 + n];
#pragma unroll
      for (int i = 0; i < 4; ++i) {
#pragma unroll
        for (int r = 0; r < 4; ++r) {
          int m = mb + i * 16 + r;  // channel o
          C[(long)m * N + n] = acc[i][j][r] * rl + bias[m] + R[(long)m * N + n];
        }
      }
    }
  }
}

// ---------------------------------------------------------------- launch
extern "C" void kernel_launch(void* const* d_in, const int* in_sizes, int n_in,
                              void* d_out, int out_size, void* d_ws, size_t ws_size,
                              hipStream_t stream) {
  const float* x     = (const float*)d_in[0];
  const float* gamma = (const float*)d_in[1];
  const float* beta  = (const float*)d_in[2];
  const float* wq    = (const float*)d_in[3];
  const float* bq    = (const float*)d_in[4];
  const float* wk    = (const float*)d_in[5];
  const float* bk    = (const float*)d_in[6];
  const float* wv    = (const float*)d_in[7];
  const float* bv    = (const float*)d_in[8];
  const float* wp    = (const float*)d_in[9];
  const float* bp    = (const float*)d_in[10];

  char* ws = (char*)d_ws;
  short* wbf   = (short*)ws;                     // [wq;wk;W'] bf16, 1.5 MB
  float* bias2 = (float*)(ws + 1572864l);        // 512 f32
  float* lsum  = (float*)(ws + 1638400l);        // 16x1024 f32, 64 KB
  short* xnt = (short*)(ws + 2097152l);          // [B,N,C] bf16, 16 MB
  short* q_t = (short*)(ws + 18874368l);         // [B,tok,ch]
  short* k_t = (short*)(ws + 35651584l);         // [B,tok,ch]
  short* u   = (short*)(ws + 52428800l);         // [B,o,tok] bf16
  short* Sbf = (short*)(ws + 69206016l);         // [B,N,N] bf16 (P')
  float2* gnpart = (float2*)Sbf;                 // 8 KB, dead before S written

  pre_kernel<<<2052, 256, 0, stream>>>(x, gnpart, wq, wk, wbf, lsum);
  wprime_kernel<<<dim3(4, 4), 256, 0, stream>>>(
      wv, wp, bv, bp, wbf + 524288, bias2);
  gn_norm_t<<<1024, 256, 0, stream>>>(x, gnpart, gamma, beta, xnt);

  qku_gemm<<<dim3(8, 12, 16), 256, 0, stream>>>(
      wbf, xnt, q_t, k_t, u, bq, bk);

  const float iscale = 0.044194173824159216f;  // 1/sqrt(512)
  // P' = exp((k_t . q_t^T)^T * scale), rowsums -> lsum
  gemm_bt<EPI_EXP_T><<<dim3(8, 8, 16), 256, 0, stream>>>(
      k_t, q_t, Sbf, nullptr, nullptr, iscale, 1024, 1024, 512,
      524288, 524288, 1048576, 0, lsum);
  // out[o][i] = (u . P'^T)/lsum[i] + bias2[o] + x
  gemm_bt<EPI_OUT><<<dim3(8, 4, 16), 256, 0, stream>>>(
      u, Sbf, d_out, bias2, x, 1.f, 512, 1024, 1024,
      524288, 1048576, 524288, 524288, lsum);
}